// Round 4
// baseline (690.410 us; speedup 1.0000x reference)
//
#include <hip/hip_runtime.h>
#include <math.h>

// Problem constants (from reference setup_inputs)
#define BQ   4
#define NQ   8400
#define NMQ  32
#define HQ   160
#define WQ   160
#define DQ   100
#define TH   16          // low-res rows per tile
#define THALO (TH + 2)   // +1 halo row top & bottom
#define OH   (TH * 4)    // 64 output rows per tile
#define OW   (WQ * 4)    // 640 output cols

// Cephes/Eigen-style f32 exp replica (classic Horner, FMA steps) — targets
// XLA:CPU's vectorized expf bit behavior. No clamping needed: |logit| < ~40.
__device__ __forceinline__ float cephes_expf(float x) {
    float m = floorf(fmaf(x, 1.44269504088896341f, 0.5f));
    float r = fmaf(m, -0.693359375f, x);
    r = fmaf(m, 2.12194440e-4f, r);
    float r2 = __fmul_rn(r, r);
    float y = 1.9875691500E-4f;
    y = fmaf(y, r, 1.3981999507E-3f);
    y = fmaf(y, r, 8.3334519073E-3f);
    y = fmaf(y, r, 4.1665795894E-2f);
    y = fmaf(y, r, 1.6666665459E-1f);
    y = fmaf(y, r, 5.0000001201E-1f);
    y = fmaf(y, r2, r);
    y = __fadd_rn(y, 1.0f);
    int im = (int)m;
    float s = __int_as_float((im + 127) << 23);   // 2^m (|m| < 60 here)
    return __fmul_rn(y, s);
}

__global__ __launch_bounds__(256) void seg_kernel(
    const float* __restrict__ mc,     // [B, N, NM] f32
    const float* __restrict__ proto,  // [B, NM, H, W] f32
    const int*   __restrict__ det,    // [B, D] int32
    int*         __restrict__ out)    // [B, D, 640, 640] int32 0/1
{
    __shared__ float tile[THALO][WQ];   // low-res sigmoid values, f32
    __shared__ float mcs[NMQ];

    const int tid = threadIdx.x;
    const int rt  = blockIdx.x;      // row tile 0..9
    const int d   = blockIdx.y;      // det 0..99
    const int b   = blockIdx.z;      // batch 0..3
    const int r0  = rt * TH;

    if (tid < NMQ) {
        int idx = det[b * DQ + d];
        mcs[tid] = mc[((size_t)b * NQ + (size_t)idx) * NMQ + tid];
    }
    __syncthreads();

    // ---- Phase 1: logits (sequential-FMA f32 dot, n ascending) + sigmoid ----
    const float* pb = proto + (size_t)b * NMQ * HQ * WQ;
    for (int p = tid; p < THALO * WQ; p += 256) {
        int h = p / WQ;
        int w = p - h * WQ;
        int gh = r0 - 1 + h;
        gh = gh < 0 ? 0 : (gh > HQ - 1 ? HQ - 1 : gh);
        const float* pp = pb + gh * WQ + w;
        float acc = 0.0f;
        #pragma unroll
        for (int n = 0; n < NMQ; ++n) {
            acc = fmaf(pp[(size_t)n * HQ * WQ], mcs[n], acc);
        }
        float e = cephes_expf(-acc);                  // exp(-logit)
        tile[h][w] = 1.0f / __fadd_rn(1.0f, e);       // IEEE divide
    }
    __syncthreads();

    // ---- Phase 2: 4x bilinear upsample (vertical first, then horizontal),
    //      replicating XLA gemm rounding: acc = fma(w1,p1, fl(w0*p0)),
    //      taps ascending; edge outputs = exact copy (single weight 1.0). ----
    const float FYB[4] = {0.625f, 0.875f, 0.125f, 0.375f};  // bottom-tap weight
    const float FYT[4] = {0.375f, 0.125f, 0.875f, 0.625f};  // top-tap weight

    int* ob = out + ((size_t)b * DQ + d) * ((size_t)OW * HQ * 4)
                  + (size_t)r0 * 4 * OW;

    for (int g = tid; g < OH * WQ; g += 256) {
        int oyl = g / WQ;              // 0..63  output row within tile
        int oxg = g - oyl * WQ;        // 0..159 group of 4 output cols
        int phase = oyl & 3;
        int iy = (oyl >> 2) + (phase >> 1);   // LDS row of top tap (halo-indexed)
        int goy = r0 * 4 + oyl;               // global output row
        bool yedge = (goy < 2) || (goy >= 4 * HQ - 2);

        int cm = (oxg == 0)      ? 0      : oxg - 1;
        int cp = (oxg == WQ - 1) ? WQ - 1 : oxg + 1;

        float tm = tile[iy][cm],     t0 = tile[iy][oxg],     tp = tile[iy][cp];
        float bm = tile[iy + 1][cm], b0 = tile[iy + 1][oxg], bp = tile[iy + 1][cp];

        float Tm, T0, Tp;
        if (yedge) {
            // jax edge: single renormalized weight == 1.0 on the clamped row,
            // which is exactly the top tap here.
            Tm = tm; T0 = t0; Tp = tp;
        } else {
            float wt = FYT[phase], wb = FYB[phase];
            Tm = fmaf(wb, bm, __fmul_rn(wt, tm));
            T0 = fmaf(wb, b0, __fmul_rn(wt, t0));
            Tp = fmaf(wb, bp, __fmul_rn(wt, tp));
        }

        // Horizontal: pixels 4c..4c+3.
        float v0, v1, v2, v3;
        if (oxg == 0) {            // global cols 0,1: exact copy of col 0
            v0 = T0; v1 = T0;
        } else {
            v0 = fmaf(0.625f, T0, __fmul_rn(0.375f, Tm));
            v1 = fmaf(0.875f, T0, __fmul_rn(0.125f, Tm));
        }
        if (oxg == WQ - 1) {       // global cols 638,639: exact copy of col 159
            v2 = T0; v3 = T0;
        } else {
            v2 = fmaf(0.125f, Tp, __fmul_rn(0.875f, T0));
            v3 = fmaf(0.375f, Tp, __fmul_rn(0.625f, T0));
        }

        int4 r;
        r.x = v0 > 0.5f ? 1 : 0;
        r.y = v1 > 0.5f ? 1 : 0;
        r.z = v2 > 0.5f ? 1 : 0;
        r.w = v3 > 0.5f ? 1 : 0;

        *(int4*)(ob + (size_t)oyl * OW + (size_t)oxg * 4) = r;
    }
}

extern "C" void kernel_launch(void* const* d_in, const int* in_sizes, int n_in,
                              void* d_out, int out_size, void* d_ws, size_t ws_size,
                              hipStream_t stream) {
    const float* mc    = (const float*)d_in[0];
    const float* proto = (const float*)d_in[1];
    const int*   det   = (const int*)d_in[2];
    int* out = (int*)d_out;

    dim3 grid(HQ / TH, DQ, BQ);   // (10, 100, 4)
    seg_kernel<<<grid, 256, 0, stream>>>(mc, proto, det, out);
}